// Round 12
// baseline (40.145 us; speedup 1.0000x reference)
//
#include <hip/hip_runtime.h>

#define BATCH  8
#define NPTS   4096
#define NSLICE 16                 // target-set split per (dir,b)
#define SLICE  (NPTS / NSLICE)    // 256 targets per block
#define TPB1   512                // 8 waves/block, 1 block/CU
#define QPT    8                  // queries per thread (4096 / 512)

// Stage 1: grid = 2 dirs x 8 batches x 16 target-slices = 256 blocks.
// Round-12 delta: NO LDS AT ALL. Targets are read straight from global with
// wave-UNIFORM addresses (uniform loop index + block-uniform base), which the
// AMDGPU backend can promote to s_load into SGPRs — freeing the vector memory
// pipes completely (no ds_read, no lgkmcnt in the VALU stream, no staging
// prologue, no __syncthreads). The -2 factor is folded into the QUERY
// registers (q' = -2q), so raw (y0,y1,y2) targets work directly:
//   e = fmaf(q'x, yx, fmaf(q'y, yy, fmaf(q'z, yz, ry)))  = ry - 2*dot(q,y)
// ry is computed on the fly (12 VALU per 4 targets, amortized over 8 queries).
// Worst case the loads stay vector ops with uniform addr -> L1-resident
// broadcast (3 KB slice panel) ~= LDS cost, i.e. neutral.
__global__ __launch_bounds__(TPB1, 2) void chamfer_stage1(
    const float* __restrict__ preds,
    const float* __restrict__ gts,
    float* __restrict__ part,     // [16 db][NSLICE][NPTS]
    float* __restrict__ out)
{
    const int blk   = blockIdx.x;
    const int slice = blk % NSLICE;
    const int db    = blk / NSLICE;    // dir*8 + b
    const int dir   = db >> 3;
    const int b     = db & 7;

    if (blk == 0 && threadIdx.x == 0) out[0] = 0.0f;

    const float* Q = dir ? gts   : preds;   // query set
    const float* T = dir ? preds : gts;     // target set

    // This thread's 8 consecutive queries (24 floats = 6 float4).
    const int q0 = threadIdx.x * QPT;
    const float4* p4 = reinterpret_cast<const float4*>(
        Q + ((size_t)b * NPTS + q0) * 3);
    const float4 v0 = p4[0], v1 = p4[1], v2 = p4[2];
    const float4 v3 = p4[3], v4 = p4[4], v5 = p4[5];

    const float ax0 = v0.x, ay0 = v0.y, az0 = v0.z;
    const float ax1 = v0.w, ay1 = v1.x, az1 = v1.y;
    const float ax2 = v1.z, ay2 = v1.w, az2 = v2.x;
    const float ax3 = v2.y, ay3 = v2.z, az3 = v2.w;
    const float ax4 = v3.x, ay4 = v3.y, az4 = v3.z;
    const float ax5 = v3.w, ay5 = v4.x, az5 = v4.y;
    const float ax6 = v4.z, ay6 = v4.w, az6 = v5.x;
    const float ax7 = v5.y, ay7 = v5.z, az7 = v5.w;

    // ||q||^2 (folded into stored partials) and scaled queries q' = -2q.
    #define PREP(k) \
        const float rx##k = fmaf(ax##k, ax##k, fmaf(ay##k, ay##k, az##k * az##k)); \
        const float qx##k = -2.0f * ax##k; \
        const float qy##k = -2.0f * ay##k; \
        const float qz##k = -2.0f * az##k;
    PREP(0) PREP(1) PREP(2) PREP(3) PREP(4) PREP(5) PREP(6) PREP(7)
    #undef PREP

    // Block's target slice, raw layout (stride 3 floats, 16B-aligned base).
    const float* Tb = T + ((size_t)b * NPTS + slice * SLICE) * 3;

    float m0 = 3.4e38f, m1 = 3.4e38f, m2 = 3.4e38f, m3 = 3.4e38f;
    float m4 = 3.4e38f, m5 = 3.4e38f, m6 = 3.4e38f, m7 = 3.4e38f;

    // 4 targets per step from 3 uniform float4 loads:
    // A=(ta.x,ta.y,ta.z) B=(ta.w,tb.x,tb.y) C=(tb.z,tb.w,tc.x) D=(tc.y,tc.z,tc.w)
    #define DO4(k) { \
        const float eA = fmaf(qx##k, ta.x, fmaf(qy##k, ta.y, fmaf(qz##k, ta.z, rA))); \
        const float eB = fmaf(qx##k, ta.w, fmaf(qy##k, tb.x, fmaf(qz##k, tb.y, rB))); \
        const float eC = fmaf(qx##k, tb.z, fmaf(qy##k, tb.w, fmaf(qz##k, tc.x, rC))); \
        const float eD = fmaf(qx##k, tc.y, fmaf(qy##k, tc.z, fmaf(qz##k, tc.w, rD))); \
        m##k = fminf(m##k, fminf(eA, eB)); \
        m##k = fminf(m##k, fminf(eC, eD)); }

    #pragma unroll 4
    for (int j = 0; j < SLICE; j += 4) {
        const float4* t4 = reinterpret_cast<const float4*>(Tb + j * 3);
        const float4 ta = t4[0];
        const float4 tb = t4[1];
        const float4 tc = t4[2];
        const float rA = fmaf(ta.x, ta.x, fmaf(ta.y, ta.y, ta.z * ta.z));
        const float rB = fmaf(ta.w, ta.w, fmaf(tb.x, tb.x, tb.y * tb.y));
        const float rC = fmaf(tb.z, tb.z, fmaf(tb.w, tb.w, tc.x * tc.x));
        const float rD = fmaf(tc.y, tc.y, fmaf(tc.z, tc.z, tc.w * tc.w));
        DO4(0) DO4(1) DO4(2) DO4(3)
        DO4(4) DO4(5) DO4(6) DO4(7)
    }
    #undef DO4

    // Coalesced 32 B/thread store with rx folded in:
    // part[db][slice][q0..q0+7] = partial_min + ||q||^2
    float4* b4 = reinterpret_cast<float4*>(
        part + ((size_t)db * NSLICE + slice) * NPTS + q0);
    b4[0] = make_float4(m0 + rx0, m1 + rx1, m2 + rx2, m3 + rx3);
    b4[1] = make_float4(m4 + rx4, m5 + rx5, m6 + rx6, m7 + rx7);
}

// Stage 2: one thread per query; min over the 16 slice-partials (rx already
// folded in), block-reduce, one atomicAdd per block.
#define TPB2 256
__global__ __launch_bounds__(TPB2) void chamfer_stage2(
    const float* __restrict__ part,
    float* __restrict__ out)
{
    const int g  = blockIdx.x * TPB2 + threadIdx.x;   // [0, 2*8*4096)
    const int db = g >> 12;
    const int q  = g & (NPTS - 1);

    const float* pp = part + (size_t)db * NSLICE * NPTS + q;
    float m = 3.4e38f;
    #pragma unroll
    for (int s = 0; s < NSLICE; ++s)
        m = fminf(m, pp[(size_t)s * NPTS]);

    float s = m;

    #pragma unroll
    for (int off = 32; off > 0; off >>= 1)
        s += __shfl_down(s, off, 64);

    __shared__ float red[TPB2 / 64];
    const int lane = threadIdx.x & 63;
    const int wid  = threadIdx.x >> 6;
    if (lane == 0) red[wid] = s;
    __syncthreads();
    if (threadIdx.x == 0) {
        float t = 0.0f;
        #pragma unroll
        for (int w = 0; w < TPB2 / 64; ++w) t += red[w];
        atomicAdd(out, t);
    }
}

extern "C" void kernel_launch(void* const* d_in, const int* in_sizes, int n_in,
                              void* d_out, int out_size, void* d_ws, size_t ws_size,
                              hipStream_t stream) {
    const float* preds = (const float*)d_in[0];
    const float* gts   = (const float*)d_in[1];
    float* out  = (float*)d_out;
    float* part = (float*)d_ws;   // 16 db x 16 slices x 4096 floats = 4 MiB

    // Only 2 dispatches: stage1 zeroes `out` itself; `part` is fully
    // written by stage 1 before stage 2 reads it — no memsets needed.
    chamfer_stage1<<<dim3(2 * BATCH * NSLICE), TPB1, 0, stream>>>(preds, gts, part, out);
    chamfer_stage2<<<dim3(2 * BATCH * NPTS / TPB2), TPB2, 0, stream>>>(part, out);
}